// Round 1
// baseline (5215.636 us; speedup 1.0000x reference)
//
#include <hip/hip_runtime.h>

// Problem constants (fixed by the reference)
#define N_NODES 20000
#define N_EDGES 100000
#define CIN     64
#define A_DIM   32
#define CCH     256
#define NBOX    128
#define FD      1024   // 4*256
#define HID     1024
#define OUT_STRIDE 2048

constexpr int TM = 64, TN = 64, KB = 32, BT = 256;

// ---------------------------------------------------------------------------
// Edge-message GEMM with gather-A and atomic scatter-C.
// Computes m[e,c] = relu( h[e,:] @ W + b )[c] * ew[e], atomically added into
// fout[dst[e]*2048 + fout_ofs + c].
// h[e,:] = [ fin[dst,0:F], fin[src,0:F]-fin[dst,0:F], ea[e,0:32] ], K = 2F+32.
// ---------------------------------------------------------------------------
__global__ __launch_bounds__(BT) void gconv_kernel(
    const float* __restrict__ fin, int fin_stride, int fin_ofs, int F,
    const int* __restrict__ src, const int* __restrict__ dst,
    const float* __restrict__ ew, const float* __restrict__ ea,
    const float* __restrict__ W, const float* __restrict__ bias,
    float* __restrict__ fout, int fout_ofs, int K)
{
    __shared__ float As[KB][TM + 1];                  // +1 pad: conflict-free stores
    __shared__ __align__(16) float Bs[KB][TN];
    __shared__ int   s_src[TM], s_dst[TM];
    __shared__ float s_ew[TM];

    const int tid = threadIdx.x;
    const int eb = blockIdx.x >> 2;                   // edge-tile
    const int cb = blockIdx.x & 3;                    // channel-tile (256/64)
    const int e0 = eb * TM;
    const int c0 = cb * TN;

    if (tid < TM) {
        int e  = e0 + tid;
        int ec = e < N_EDGES ? e : N_EDGES - 1;
        s_src[tid] = src[ec];
        s_dst[tid] = dst[ec];
        s_ew[tid]  = (e < N_EDGES) ? ew[e] : 0.f;
    }
    __syncthreads();

    const int tx = tid & 15, ty = tid >> 4;           // tx: channel grp, ty: edge grp
    const int F2 = 2 * F;
    float acc[4][4] = {{0.f, 0.f, 0.f, 0.f}};

    for (int k0 = 0; k0 < K; k0 += KB) {
        // Stage A (64 edges x 32 k), transposed As[k][e]; lanes 0..31 read
        // consecutive k of one edge's source row -> coalesced.
        #pragma unroll
        for (int l = 0; l < (KB * TM) / BT; ++l) {
            int idx = tid + l * BT;
            int kk  = idx & (KB - 1);
            int e   = idx >> 5;
            int k   = k0 + kk;
            int ge  = e0 + e;
            float v = 0.f;
            if (ge < N_EDGES) {
                if (k < F) {
                    v = fin[(long)s_dst[e] * fin_stride + fin_ofs + k];
                } else if (k < F2) {
                    int kf = k - F;
                    v = fin[(long)s_src[e] * fin_stride + fin_ofs + kf]
                      - fin[(long)s_dst[e] * fin_stride + fin_ofs + kf];
                } else {
                    v = ea[(long)ge * A_DIM + (k - F2)];
                }
            }
            As[kk][e] = v;
        }
        // Stage B (32 k x 64 channels)
        #pragma unroll
        for (int l = 0; l < (KB * TN) / BT; ++l) {
            int idx = tid + l * BT;
            int cc  = idx & (TN - 1);
            int kk  = idx >> 6;
            Bs[kk][cc] = W[(long)(k0 + kk) * CCH + c0 + cc];
        }
        __syncthreads();
        #pragma unroll
        for (int kk = 0; kk < KB; ++kk) {
            float a[4];
            #pragma unroll
            for (int i = 0; i < 4; ++i) a[i] = As[kk][ty * 4 + i];
            const float4 b4 = *(const float4*)(&Bs[kk][tx * 4]);
            const float b[4] = {b4.x, b4.y, b4.z, b4.w};
            #pragma unroll
            for (int i = 0; i < 4; ++i)
                #pragma unroll
                for (int j = 0; j < 4; ++j)
                    acc[i][j] = fmaf(a[i], b[j], acc[i][j]);
        }
        __syncthreads();
    }

    // Epilogue: relu(+bias) * ew, atomic scatter to dst rows
    #pragma unroll
    for (int i = 0; i < 4; ++i) {
        int el = ty * 4 + i;
        int ge = e0 + el;
        if (ge < N_EDGES) {
            float wgt = s_ew[el];
            long  orow = (long)s_dst[el] * OUT_STRIDE + fout_ofs + c0 + tx * 4;
            #pragma unroll
            for (int j = 0; j < 4; ++j) {
                float m = acc[i][j] + bias[c0 + tx * 4 + j];
                m = fmaxf(m, 0.f) * wgt;
                atomicAdd(&fout[orow + j], m);
            }
        }
    }
}

// ---------------------------------------------------------------------------
// Dense GEMM with 2-source concatenated A:  out = relu([in0|in1] @ W + b)
// A row r: cols 0..C0-1 from in0[r*s0+o0+..], cols C0..K-1 from in1[r*s1+o1+..]
// ---------------------------------------------------------------------------
__global__ __launch_bounds__(BT) void dense_kernel(
    const float* __restrict__ in0, int s0, int o0, int C0,
    const float* __restrict__ in1, int s1, int o1,
    const float* __restrict__ W, const float* __restrict__ bias,
    float* __restrict__ out, int so, int oo,
    int M, int K, int Nc, int nbc)
{
    __shared__ float As[KB][TM + 1];
    __shared__ __align__(16) float Bs[KB][TN];

    const int tid = threadIdx.x;
    const int rb  = blockIdx.x / nbc;
    const int cbi = blockIdx.x % nbc;
    const int r0 = rb * TM;
    const int c0 = cbi * TN;
    const int tx = tid & 15, ty = tid >> 4;
    float acc[4][4] = {{0.f, 0.f, 0.f, 0.f}};

    for (int k0 = 0; k0 < K; k0 += KB) {
        #pragma unroll
        for (int l = 0; l < (KB * TM) / BT; ++l) {
            int idx = tid + l * BT;
            int kk  = idx & (KB - 1);
            int r   = idx >> 5;
            int k   = k0 + kk;
            int gr  = r0 + r;
            float v = 0.f;
            if (gr < M) {
                v = (k < C0) ? in0[(long)gr * s0 + o0 + k]
                             : in1[(long)gr * s1 + o1 + (k - C0)];
            }
            As[kk][r] = v;
        }
        #pragma unroll
        for (int l = 0; l < (KB * TN) / BT; ++l) {
            int idx = tid + l * BT;
            int cc  = idx & (TN - 1);
            int kk  = idx >> 6;
            Bs[kk][cc] = W[(long)(k0 + kk) * Nc + c0 + cc];
        }
        __syncthreads();
        #pragma unroll
        for (int kk = 0; kk < KB; ++kk) {
            float a[4];
            #pragma unroll
            for (int i = 0; i < 4; ++i) a[i] = As[kk][ty * 4 + i];
            const float4 b4 = *(const float4*)(&Bs[kk][tx * 4]);
            const float b[4] = {b4.x, b4.y, b4.z, b4.w};
            #pragma unroll
            for (int i = 0; i < 4; ++i)
                #pragma unroll
                for (int j = 0; j < 4; ++j)
                    acc[i][j] = fmaf(a[i], b[j], acc[i][j]);
        }
        __syncthreads();
    }

    #pragma unroll
    for (int i = 0; i < 4; ++i) {
        int gr = r0 + ty * 4 + i;
        if (gr < M) {
            #pragma unroll
            for (int j = 0; j < 4; ++j) {
                float v = acc[i][j] + bias[c0 + tx * 4 + j];
                out[(long)gr * so + oo + c0 + tx * 4 + j] = fmaxf(v, 0.f);
            }
        }
    }
}

// ---------------------------------------------------------------------------
// Utility kernels
// ---------------------------------------------------------------------------
__global__ void zero_kernel(float* p, long n) {
    long stride = (long)gridDim.x * blockDim.x;
    for (long i = (long)blockIdx.x * blockDim.x + threadIdx.x; i < n; i += stride)
        p[i] = 0.f;
}

// zero one 256-wide column block of the [rows,2048] output matrix
__global__ void zero_cols_kernel(float* base, int ofs, long rows) {
    long total = rows * CCH;
    long stride = (long)gridDim.x * blockDim.x;
    for (long i = (long)blockIdx.x * blockDim.x + threadIdx.x; i < total; i += stride) {
        long r = i >> 8; int c = (int)(i & 255);
        base[r * OUT_STRIDE + ofs + c] = 0.f;
    }
}

// copy column block src_ofs -> dst_ofs (residual init: f_{i+1} := f_i)
__global__ void copy_cols_kernel(float* base, int src_ofs, int dst_ofs, long rows) {
    long total = rows * CCH;
    long stride = (long)gridDim.x * blockDim.x;
    for (long i = (long)blockIdx.x * blockDim.x + threadIdx.x; i < total; i += stride) {
        long r = i >> 8; int c = (int)(i & 255);
        base[r * OUT_STRIDE + dst_ofs + c] = base[r * OUT_STRIDE + src_ofs + c];
    }
}

__global__ void box_accum_kernel(const float* __restrict__ fs_cat,
                                 const int* __restrict__ bbox,
                                 float* __restrict__ sums) {
    long total = (long)N_NODES * FD;
    long stride = (long)gridDim.x * blockDim.x;
    for (long i = (long)blockIdx.x * blockDim.x + threadIdx.x; i < total; i += stride) {
        int n = (int)(i >> 10);
        int c = (int)(i & 1023);
        atomicAdd(&sums[(long)bbox[n] * FD + c], fs_cat[i]);
    }
}

__global__ void box_count_kernel(const int* __restrict__ bbox, float* __restrict__ cnt) {
    int n = blockIdx.x * blockDim.x + threadIdx.x;
    if (n < N_NODES) atomicAdd(&cnt[bbox[n]], 1.f);
}

__global__ void box_mean_kernel(const float* __restrict__ sums,
                                const float* __restrict__ cnt,
                                float* __restrict__ out_super) {
    long i = (long)blockIdx.x * blockDim.x + threadIdx.x;
    if (i < (long)NBOX * FD) {
        int b = (int)(i >> 10);
        int c = (int)(i & 1023);
        out_super[(long)b * OUT_STRIDE + HID + c] = sums[i] / fmaxf(cnt[b], 1.f);
    }
}

// ---------------------------------------------------------------------------
extern "C" void kernel_launch(void* const* d_in, const int* in_sizes, int n_in,
                              void* d_out, int out_size, void* d_ws, size_t ws_size,
                              hipStream_t stream) {
    const float* x      = (const float*)d_in[0];
    const int*   edges  = (const int*)d_in[1];
    const float* ew     = (const float*)d_in[2];
    const float* ea     = (const float*)d_in[3];
    const int*   bbox   = (const int*)d_in[4];
    const float* W_msg0 = (const float*)d_in[6];
    const float* b_msg0 = (const float*)d_in[7];
    const float* W_sup0 = (const float*)d_in[8];
    const float* b_sup0 = (const float*)d_in[9];
    const float* W_msg  = (const float*)d_in[10];   // [3,544,256]
    const float* b_msg  = (const float*)d_in[11];   // [3,256]
    const float* W_sup  = (const float*)d_in[12];   // [3,512,256]
    const float* b_sup  = (const float*)d_in[13];   // [3,256]
    const float* W_fuse = (const float*)d_in[14];   // [1024,1024]
    const float* b_fuse = (const float*)d_in[15];
    const float* W_fsup = (const float*)d_in[16];
    const float* b_fsup = (const float*)d_in[17];

    float* out       = (float*)d_out;                       // [N,2048]
    float* out_super = out + (long)N_NODES * OUT_STRIDE;    // [B,2048]
    float* fs_cat    = (float*)d_ws;                        // [N,1024]
    float* box_sums  = fs_cat + (long)N_NODES * FD;         // [B,1024]
    float* box_cnt   = box_sums + (long)NBOX * FD;          // [B]

    const int* srcp = edges;            // edges[0] = src
    const int* dstp = edges + N_EDGES;  // edges[1] = dst

    const int GE = ((N_EDGES + TM - 1) / TM) * 4;   // 1563*4 gconv blocks
    const int GN = ((N_NODES + TM - 1) / TM);       // 313 row-tiles

    // 1. init accumulators (d_out / d_ws are poisoned before every launch)
    zero_cols_kernel<<<1024, BT, 0, stream>>>(out, HID, N_NODES);
    zero_kernel<<<256, BT, 0, stream>>>(box_sums, (long)NBOX * FD + NBOX);

    // 2. head gconv: f0 into out cols [1024,1280)
    gconv_kernel<<<GE, BT, 0, stream>>>(x, CIN, 0, CIN, srcp, dstp, ew, ea,
                                        W_msg0, b_msg0, out, HID, 2 * CIN + A_DIM);
    // 3. head super: fs0 = relu([f0|x] @ W_sup0 + b)
    dense_kernel<<<GN * 4, BT, 0, stream>>>(out, OUT_STRIDE, HID, CCH,
                                            x, CIN, 0, W_sup0, b_sup0,
                                            fs_cat, FD, 0, N_NODES, CCH + CIN, CCH, 4);
    // 4. ResBlocks
    for (int i = 0; i < 3; ++i) {
        int fi = HID + CCH * i, fo = HID + CCH * (i + 1);
        copy_cols_kernel<<<1024, BT, 0, stream>>>(out, fi, fo, N_NODES); // residual init
        gconv_kernel<<<GE, BT, 0, stream>>>(out, OUT_STRIDE, fi, CCH, srcp, dstp, ew, ea,
                                            W_msg + (long)i * 544 * CCH, b_msg + i * CCH,
                                            out, fo, 2 * CCH + A_DIM);
        dense_kernel<<<GN * 4, BT, 0, stream>>>(out, OUT_STRIDE, fo, CCH,
                                                fs_cat, FD, CCH * i,
                                                W_sup + (long)i * 512 * CCH, b_sup + i * CCH,
                                                fs_cat, FD, CCH * (i + 1),
                                                N_NODES, 2 * CCH, CCH, 4);
    }
    // 5. fusion: out cols [0,1024) = relu(feats_cat @ W_fuse + b)
    dense_kernel<<<GN * 16, BT, 0, stream>>>(out, OUT_STRIDE, HID, FD,
                                             out, 0, 0, W_fuse, b_fuse,
                                             out, OUT_STRIDE, 0, N_NODES, FD, HID, 16);
    // 6. super path: box mean + fusion_sup
    box_accum_kernel<<<4096, BT, 0, stream>>>(fs_cat, bbox, box_sums);
    box_count_kernel<<<(N_NODES + BT - 1) / BT, BT, 0, stream>>>(bbox, box_cnt);
    box_mean_kernel<<<(NBOX * FD) / BT, BT, 0, stream>>>(box_sums, box_cnt, out_super);
    dense_kernel<<<2 * 16, BT, 0, stream>>>(out_super, OUT_STRIDE, HID, FD,
                                            out_super, 0, 0, W_fsup, b_fsup,
                                            out_super, OUT_STRIDE, 0, NBOX, FD, HID, 16);
}

// Round 2
// 1517.791 us; speedup vs baseline: 3.4363x; 3.4363x over previous
//
#include <hip/hip_runtime.h>

#define N_NODES 20000
#define N_EDGES 100000
#define CIN     64
#define A_DIM   32
#define CCH     256
#define NBOX    128
#define FD      1024
#define HID     1024
#define OUT_STRIDE 2048

typedef __attribute__((ext_vector_type(8))) short          short8;
typedef __attribute__((ext_vector_type(8))) unsigned short ushort8;
typedef __attribute__((ext_vector_type(4))) float          floatx4;

__device__ __forceinline__ unsigned short f2bf(float f) {
    unsigned int u = __float_as_uint(f);
    u += 0x7fff + ((u >> 16) & 1);          // round-to-nearest-even
    return (unsigned short)(u >> 16);
}
__device__ __forceinline__ float bf2f(unsigned short h) {
    return __uint_as_float(((unsigned int)h) << 16);
}

// load 16 consecutive fp32 (64B-aligned) -> two bf16x8 halves
__device__ __forceinline__ void pack16(const float* __restrict__ p,
                                       ushort8& h0, ushort8& h1) {
    const float4* q = (const float4*)p;
    float4 a = q[0], b = q[1], c = q[2], d = q[3];
    h0 = (ushort8){f2bf(a.x), f2bf(a.y), f2bf(a.z), f2bf(a.w),
                   f2bf(b.x), f2bf(b.y), f2bf(b.z), f2bf(b.w)};
    h1 = (ushort8){f2bf(c.x), f2bf(c.y), f2bf(c.z), f2bf(c.w),
                   f2bf(d.x), f2bf(d.y), f2bf(d.z), f2bf(d.w)};
}
// (src - dst) variant for gconv middle segment
__device__ __forceinline__ void pack16_sub(const float* __restrict__ ps,
                                           const float* __restrict__ pd,
                                           ushort8& h0, ushort8& h1) {
    const float4* qs = (const float4*)ps;
    const float4* qd = (const float4*)pd;
    float v[16];
    #pragma unroll
    for (int i = 0; i < 4; ++i) {
        float4 s = qs[i], d = qd[i];
        v[i*4+0] = s.x - d.x; v[i*4+1] = s.y - d.y;
        v[i*4+2] = s.z - d.z; v[i*4+3] = s.w - d.w;
    }
    h0 = (ushort8){f2bf(v[0]),f2bf(v[1]),f2bf(v[2]),f2bf(v[3]),
                   f2bf(v[4]),f2bf(v[5]),f2bf(v[6]),f2bf(v[7])};
    h1 = (ushort8){f2bf(v[8]),f2bf(v[9]),f2bf(v[10]),f2bf(v[11]),
                   f2bf(v[12]),f2bf(v[13]),f2bf(v[14]),f2bf(v[15])};
}

// ---------------------------------------------------------------------------
// Dense MFMA GEMM, 128x128 tile, A = [src0 | src1] row-gathered & converted,
// B = pre-transposed bf16 Wt[n][k]. Epilogue: relu(+bias) -> fp32 and/or bf16.
// ---------------------------------------------------------------------------
__global__ __launch_bounds__(256) void mfma_dense(
    const float* __restrict__ src0, int s0, int o0, int C0,
    const float* __restrict__ src1f, const unsigned short* __restrict__ src1b,
    int s1, int o1,
    const unsigned short* __restrict__ Wt, const float* __restrict__ bias,
    float* __restrict__ outf, int sof, int oof,
    unsigned short* __restrict__ outb, int sob, int oob,
    int M, int K, int nbc)
{
    __shared__ unsigned short As[128 * 32];
    __shared__ unsigned short Bs[128 * 32];

    const int tid  = threadIdx.x;
    const int rb   = blockIdx.x / nbc, cb = blockIdx.x % nbc;
    const int r0   = rb * 128, c0 = cb * 128;
    const int wave = tid >> 6, lane = tid & 63;
    const int quad = lane >> 4, l16 = lane & 15;
    const int wm   = (wave & 1) * 64, wn = (wave >> 1) * 64;
    const int sr   = tid & 127;          // stage row (lane-major: 2-way LDS only)
    const int skc  = (tid >> 7) * 16;    // stage k-chunk 0|16

    floatx4 acc[4][4];
    #pragma unroll
    for (int i = 0; i < 4; ++i)
        #pragma unroll
        for (int j = 0; j < 4; ++j) acc[i][j] = (floatx4){0.f, 0.f, 0.f, 0.f};

    const int gr = r0 + sr;
    const int gn = c0 + sr;

    for (int k0 = 0; k0 < K; k0 += 32) {
        const int k = k0 + skc;
        ushort8 h0, h1;
        if (gr >= M) {
            h0 = (ushort8){0,0,0,0,0,0,0,0}; h1 = h0;
        } else if (k < C0) {
            pack16(src0 + (long)gr * s0 + o0 + k, h0, h1);
        } else if (src1b) {
            const ushort8* p = (const ushort8*)(src1b + (long)gr * s1 + o1 + (k - C0));
            h0 = p[0]; h1 = p[1];
        } else {
            pack16(src1f + (long)gr * s1 + o1 + (k - C0), h0, h1);
        }
        *(ushort8*)(&As[sr * 32 + skc])     = h0;
        *(ushort8*)(&As[sr * 32 + skc + 8]) = h1;

        const ushort8* wp = (const ushort8*)(Wt + (long)gn * K + k0 + skc);
        *(ushort8*)(&Bs[sr * 32 + skc])     = wp[0];
        *(ushort8*)(&Bs[sr * 32 + skc + 8]) = wp[1];

        __syncthreads();

        short8 af[4], bfr[4];
        #pragma unroll
        for (int mt = 0; mt < 4; ++mt)
            af[mt] = *(const short8*)(&As[(wm + mt * 16 + l16) * 32 + quad * 8]);
        #pragma unroll
        for (int nt = 0; nt < 4; ++nt)
            bfr[nt] = *(const short8*)(&Bs[(wn + nt * 16 + l16) * 32 + quad * 8]);
        #pragma unroll
        for (int mt = 0; mt < 4; ++mt)
            #pragma unroll
            for (int nt = 0; nt < 4; ++nt)
                acc[mt][nt] = __builtin_amdgcn_mfma_f32_16x16x32_bf16(
                    af[mt], bfr[nt], acc[mt][nt], 0, 0, 0);
        __syncthreads();
    }

    #pragma unroll
    for (int nt = 0; nt < 4; ++nt) {
        const int gc = c0 + wn + nt * 16 + l16;
        const float bv = bias[gc];
        #pragma unroll
        for (int mt = 0; mt < 4; ++mt) {
            #pragma unroll
            for (int reg = 0; reg < 4; ++reg) {
                const int grr = r0 + wm + mt * 16 + quad * 4 + reg;
                if (grr < M) {
                    float v = fmaxf(acc[mt][nt][reg] + bv, 0.f);
                    if (outf) outf[(long)grr * sof + oof + gc] = v;
                    if (outb) outb[(long)grr * sob + oob + gc] = f2bf(v);
                }
            }
        }
    }
}

// ---------------------------------------------------------------------------
// Edge-message MFMA GEMM: A rows gathered per edge [f_dst | f_src-f_dst | ea],
// B = bf16 Wt[n][k]. Epilogue relu(+bias)*ew, atomic scatter-add to dst rows.
// ---------------------------------------------------------------------------
__global__ __launch_bounds__(256) void mfma_gconv(
    const float* __restrict__ fin, int fst, int fofs, int F,
    const int* __restrict__ srcI, const int* __restrict__ dstI,
    const float* __restrict__ ew, const float* __restrict__ ea,
    const unsigned short* __restrict__ Wt, const float* __restrict__ bias,
    float* __restrict__ fout, int oofs, int K)
{
    __shared__ unsigned short As[128 * 32];
    __shared__ unsigned short Bs[128 * 32];
    __shared__ int   s_src[128], s_dst[128];
    __shared__ float s_ew[128];

    const int tid  = threadIdx.x;
    const int eb   = blockIdx.x >> 1, cb = blockIdx.x & 1;
    const int e0   = eb * 128, c0 = cb * 128;
    const int wave = tid >> 6, lane = tid & 63;
    const int quad = lane >> 4, l16 = lane & 15;
    const int wm   = (wave & 1) * 64, wn = (wave >> 1) * 64;
    const int sr   = tid & 127;
    const int skc  = (tid >> 7) * 16;

    if (tid < 128) {
        int e  = e0 + tid;
        int ec = e < N_EDGES ? e : N_EDGES - 1;
        s_src[tid] = srcI[ec];
        s_dst[tid] = dstI[ec];
        s_ew[tid]  = (e < N_EDGES) ? ew[e] : 0.f;
    }
    __syncthreads();

    floatx4 acc[4][4];
    #pragma unroll
    for (int i = 0; i < 4; ++i)
        #pragma unroll
        for (int j = 0; j < 4; ++j) acc[i][j] = (floatx4){0.f, 0.f, 0.f, 0.f};

    const int ge = e0 + sr;
    const int gn = c0 + sr;
    const int F2 = 2 * F;

    for (int k0 = 0; k0 < K; k0 += 32) {
        const int k = k0 + skc;
        ushort8 h0, h1;
        if (ge >= N_EDGES) {
            h0 = (ushort8){0,0,0,0,0,0,0,0}; h1 = h0;
        } else if (k < F) {
            pack16(fin + (long)s_dst[sr] * fst + fofs + k, h0, h1);
        } else if (k < F2) {
            const int kf = k - F;
            pack16_sub(fin + (long)s_src[sr] * fst + fofs + kf,
                       fin + (long)s_dst[sr] * fst + fofs + kf, h0, h1);
        } else {
            pack16(ea + (long)ge * A_DIM + (k - F2), h0, h1);
        }
        *(ushort8*)(&As[sr * 32 + skc])     = h0;
        *(ushort8*)(&As[sr * 32 + skc + 8]) = h1;

        const ushort8* wp = (const ushort8*)(Wt + (long)gn * K + k0 + skc);
        *(ushort8*)(&Bs[sr * 32 + skc])     = wp[0];
        *(ushort8*)(&Bs[sr * 32 + skc + 8]) = wp[1];

        __syncthreads();

        short8 af[4], bfr[4];
        #pragma unroll
        for (int mt = 0; mt < 4; ++mt)
            af[mt] = *(const short8*)(&As[(wm + mt * 16 + l16) * 32 + quad * 8]);
        #pragma unroll
        for (int nt = 0; nt < 4; ++nt)
            bfr[nt] = *(const short8*)(&Bs[(wn + nt * 16 + l16) * 32 + quad * 8]);
        #pragma unroll
        for (int mt = 0; mt < 4; ++mt)
            #pragma unroll
            for (int nt = 0; nt < 4; ++nt)
                acc[mt][nt] = __builtin_amdgcn_mfma_f32_16x16x32_bf16(
                    af[mt], bfr[nt], acc[mt][nt], 0, 0, 0);
        __syncthreads();
    }

    #pragma unroll
    for (int nt = 0; nt < 4; ++nt) {
        const int gc = c0 + wn + nt * 16 + l16;
        const float bv = bias[gc];
        #pragma unroll
        for (int mt = 0; mt < 4; ++mt) {
            #pragma unroll
            for (int reg = 0; reg < 4; ++reg) {
                const int el = wm + mt * 16 + quad * 4 + reg;
                const int geo = e0 + el;
                if (geo < N_EDGES) {
                    float m = fmaxf(acc[mt][nt][reg] + bv, 0.f) * s_ew[el];
                    atomicAdd(&fout[(long)s_dst[el] * OUT_STRIDE + oofs + gc], m);
                }
            }
        }
    }
}

// ---------------------------------------------------------------------------
// Utility kernels
// ---------------------------------------------------------------------------
__global__ void transpose_w(const float* __restrict__ W, unsigned short* __restrict__ Wt,
                            int K, int N) {
    int i = blockIdx.x * blockDim.x + threadIdx.x;
    if (i < K * N) {
        int k = i / N, n = i % N;
        Wt[(long)n * K + k] = f2bf(W[i]);
    }
}

__global__ void zero_kernel(float* p, long n) {
    long stride = (long)gridDim.x * blockDim.x;
    for (long i = (long)blockIdx.x * blockDim.x + threadIdx.x; i < n; i += stride)
        p[i] = 0.f;
}

__global__ void zero_cols_kernel(float* base, int ofs, long rows) {
    long total = rows * CCH;
    long stride = (long)gridDim.x * blockDim.x;
    for (long i = (long)blockIdx.x * blockDim.x + threadIdx.x; i < total; i += stride) {
        long r = i >> 8; int c = (int)(i & 255);
        base[r * OUT_STRIDE + ofs + c] = 0.f;
    }
}

__global__ void copy_cols_kernel(float* base, int src_ofs, int dst_ofs, long rows) {
    long total = rows * CCH;
    long stride = (long)gridDim.x * blockDim.x;
    for (long i = (long)blockIdx.x * blockDim.x + threadIdx.x; i < total; i += stride) {
        long r = i >> 8; int c = (int)(i & 255);
        base[r * OUT_STRIDE + dst_ofs + c] = base[r * OUT_STRIDE + src_ofs + c];
    }
}

__global__ void box_accum_kernel(const unsigned short* __restrict__ fsbf,
                                 const int* __restrict__ bbox,
                                 float* __restrict__ sums) {
    long total = (long)N_NODES * FD;
    long stride = (long)gridDim.x * blockDim.x;
    for (long i = (long)blockIdx.x * blockDim.x + threadIdx.x; i < total; i += stride) {
        int n = (int)(i >> 10);
        int c = (int)(i & 1023);
        atomicAdd(&sums[(long)bbox[n] * FD + c], bf2f(fsbf[i]));
    }
}

__global__ void box_count_kernel(const int* __restrict__ bbox, float* __restrict__ cnt) {
    int n = blockIdx.x * blockDim.x + threadIdx.x;
    if (n < N_NODES) atomicAdd(&cnt[bbox[n]], 1.f);
}

__global__ void box_mean_kernel(const float* __restrict__ sums,
                                const float* __restrict__ cnt,
                                float* __restrict__ out_super,
                                float* __restrict__ fsmean) {
    long i = (long)blockIdx.x * blockDim.x + threadIdx.x;
    if (i < (long)NBOX * FD) {
        int b = (int)(i >> 10);
        int c = (int)(i & 1023);
        float m = sums[i] / fmaxf(cnt[b], 1.f);
        out_super[(long)b * OUT_STRIDE + HID + c] = m;
        fsmean[i] = m;
    }
}

// ---------------------------------------------------------------------------
extern "C" void kernel_launch(void* const* d_in, const int* in_sizes, int n_in,
                              void* d_out, int out_size, void* d_ws, size_t ws_size,
                              hipStream_t stream) {
    const float* x      = (const float*)d_in[0];
    const int*   edges  = (const int*)d_in[1];
    const float* ew     = (const float*)d_in[2];
    const float* ea     = (const float*)d_in[3];
    const int*   bbox   = (const int*)d_in[4];
    const float* W_msg0 = (const float*)d_in[6];
    const float* b_msg0 = (const float*)d_in[7];
    const float* W_sup0 = (const float*)d_in[8];
    const float* b_sup0 = (const float*)d_in[9];
    const float* W_msg  = (const float*)d_in[10];
    const float* b_msg  = (const float*)d_in[11];
    const float* W_sup  = (const float*)d_in[12];
    const float* b_sup  = (const float*)d_in[13];
    const float* W_fuse = (const float*)d_in[14];
    const float* b_fuse = (const float*)d_in[15];
    const float* W_fsup = (const float*)d_in[16];
    const float* b_fsup = (const float*)d_in[17];

    float* out       = (float*)d_out;
    float* out_super = out + (long)N_NODES * OUT_STRIDE;

    // workspace layout
    unsigned short* fsbf   = (unsigned short*)d_ws;                 // [20000,1024] bf16
    float* box_sums        = (float*)((char*)d_ws + (long)N_NODES * FD * 2);
    float* box_cnt         = box_sums + (long)NBOX * FD;
    float* fsmean          = box_cnt + NBOX;
    unsigned short* wts    = (unsigned short*)(fsmean + (long)NBOX * FD);
    unsigned short* wt_msg0 = wts;
    unsigned short* wt_sup0 = wt_msg0 + 256 * 160;
    unsigned short* wt_msg  = wt_sup0 + 256 * 320;      // 3 x [256][544]
    unsigned short* wt_sup  = wt_msg + 3 * 256 * 544;   // 3 x [256][512]
    unsigned short* wt_fuse = wt_sup + 3 * 256 * 512;   // [1024][1024]
    unsigned short* wt_fsup = wt_fuse + 1024 * 1024;

    const int* srcp = edges;
    const int* dstp = edges + N_EDGES;

    const int GRB = (N_NODES + 127) / 128;   // 157 node row-blocks
    const int GEB = (N_EDGES + 127) / 128;   // 782 edge blocks

    // 0. transpose + convert weights to bf16 [N][K]
    auto T = [&](const float* W, unsigned short* Wt, int K, int N) {
        int tot = K * N;
        transpose_w<<<(tot + 255) / 256, 256, 0, stream>>>(W, Wt, K, N);
    };
    T(W_msg0, wt_msg0, 160, 256);
    T(W_sup0, wt_sup0, 320, 256);
    for (int i = 0; i < 3; ++i) {
        T(W_msg + (long)i * 544 * 256, wt_msg + (long)i * 256 * 544, 544, 256);
        T(W_sup + (long)i * 512 * 256, wt_sup + (long)i * 256 * 512, 512, 256);
    }
    T(W_fuse, wt_fuse, 1024, 1024);
    T(W_fsup, wt_fsup, 1024, 1024);

    // 1. init accumulators
    zero_cols_kernel<<<1024, 256, 0, stream>>>(out, HID, N_NODES);          // f0 block
    zero_kernel<<<256, 256, 0, stream>>>(box_sums, (long)NBOX * FD + NBOX); // sums+cnt

    // 2. head gconv: f0 -> out cols [1024,1280)
    mfma_gconv<<<GEB * 2, 256, 0, stream>>>(x, CIN, 0, CIN, srcp, dstp, ew, ea,
                                            wt_msg0, b_msg0, out, HID, 2 * CIN + A_DIM);
    // 3. head super: fs0 = relu([f0 | x] W) -> fsbf cols [0,256)
    mfma_dense<<<GRB * 2, 256, 0, stream>>>(out, OUT_STRIDE, HID, CCH,
                                            x, nullptr, CIN, 0,
                                            wt_sup0, b_sup0,
                                            nullptr, 0, 0, fsbf, FD, 0,
                                            N_NODES, CCH + CIN, 2);
    // 4. ResBlocks
    for (int i = 0; i < 3; ++i) {
        const int fi = HID + CCH * i, fo = HID + CCH * (i + 1);
        copy_cols_kernel<<<1024, 256, 0, stream>>>(out, fi, fo, N_NODES);
        mfma_gconv<<<GEB * 2, 256, 0, stream>>>(out, OUT_STRIDE, fi, CCH, srcp, dstp, ew, ea,
                                                wt_msg + (long)i * 256 * 544, b_msg + i * CCH,
                                                out, fo, 2 * CCH + A_DIM);
        mfma_dense<<<GRB * 2, 256, 0, stream>>>(out, OUT_STRIDE, fo, CCH,
                                                nullptr, fsbf, FD, CCH * i,
                                                wt_sup + (long)i * 256 * 512, b_sup + i * CCH,
                                                nullptr, 0, 0, fsbf, FD, CCH * (i + 1),
                                                N_NODES, 2 * CCH, 2);
    }
    // 5. fusion: out cols [0,1024) = relu(feats_cat @ W_fuse + b)
    mfma_dense<<<GRB * 8, 256, 0, stream>>>(out, OUT_STRIDE, HID, FD,
                                            nullptr, nullptr, 0, 0,
                                            wt_fuse, b_fuse,
                                            out, OUT_STRIDE, 0, nullptr, 0, 0,
                                            N_NODES, FD, 8);
    // 6. super path: box mean + fusion_sup
    box_accum_kernel<<<4096, 256, 0, stream>>>(fsbf, bbox, box_sums);
    box_count_kernel<<<(N_NODES + 255) / 256, 256, 0, stream>>>(bbox, box_cnt);
    box_mean_kernel<<<(NBOX * FD) / 256, 256, 0, stream>>>(box_sums, box_cnt,
                                                           out_super, fsmean);
    mfma_dense<<<8, 256, 0, stream>>>(fsmean, FD, 0, FD,
                                      nullptr, nullptr, 0, 0,
                                      wt_fsup, b_fsup,
                                      out_super, OUT_STRIDE, 0, nullptr, 0, 0,
                                      NBOX, FD, 8);
}

// Round 3
// 1155.876 us; speedup vs baseline: 4.5123x; 1.3131x over previous
//
#include <hip/hip_runtime.h>

#define N_NODES 20000
#define N_EDGES 100000
#define CIN     64
#define A_DIM   32
#define CCH     256
#define NBOX    128
#define FD      1024
#define HID     1024
#define OUT_STRIDE 2048

typedef __attribute__((ext_vector_type(8))) short          short8;
typedef __attribute__((ext_vector_type(8))) unsigned short ushort8;
typedef __attribute__((ext_vector_type(4))) unsigned short ushort4v;
typedef __attribute__((ext_vector_type(4))) float          floatx4;

#define AS_STRIDE 40   // shorts; 80B row stride -> LDS start banks cycle all 8 groups

__device__ __forceinline__ unsigned short f2bf(float f) {
    unsigned int u = __float_as_uint(f);
    u += 0x7fff + ((u >> 16) & 1);
    return (unsigned short)(u >> 16);
}
__device__ __forceinline__ float bf2f(unsigned short h) {
    return __uint_as_float(((unsigned int)h) << 16);
}

__device__ __forceinline__ void pack16(const float* __restrict__ p,
                                       ushort8& h0, ushort8& h1) {
    const float4* q = (const float4*)p;
    float4 a = q[0], b = q[1], c = q[2], d = q[3];
    h0 = (ushort8){f2bf(a.x), f2bf(a.y), f2bf(a.z), f2bf(a.w),
                   f2bf(b.x), f2bf(b.y), f2bf(b.z), f2bf(b.w)};
    h1 = (ushort8){f2bf(c.x), f2bf(c.y), f2bf(c.z), f2bf(c.w),
                   f2bf(d.x), f2bf(d.y), f2bf(d.z), f2bf(d.w)};
}

// ---------------------------------------------------------------------------
// Dense MFMA GEMM, 128x128 tile. A = [src0 | src1] rows (optional row remap on
// src0 via ridx0), fp32->bf16 converted or raw bf16. B = bf16 Wt[n][k].
// Epilogue: (+bias, relu optional) -> fp32 out and/or bf16 out; rmode packs
// bf16 rows 8-per-out-row into out[:,0:1024) scratch (for the R matrix).
// ---------------------------------------------------------------------------
__global__ __launch_bounds__(256) void mfma_dense(
    const float* __restrict__ src0, int s0, int o0, int C0,
    const int* __restrict__ ridx0,
    const float* __restrict__ src1f, const unsigned short* __restrict__ src1b,
    int s1, int o1,
    const unsigned short* __restrict__ Wt, const float* __restrict__ bias,
    int do_relu,
    float* __restrict__ outf, int sof, int oof,
    unsigned short* __restrict__ outb, int sob, int oob, int rmode,
    int M, int K, int nbc)
{
    __shared__ __align__(16) unsigned short As[128 * AS_STRIDE];
    __shared__ __align__(16) unsigned short Bs[128 * AS_STRIDE];

    const int tid  = threadIdx.x;
    const int rb   = blockIdx.x / nbc, cb = blockIdx.x % nbc;
    const int r0   = rb * 128, c0 = cb * 128;
    const int wave = tid >> 6, lane = tid & 63;
    const int quad = lane >> 4, l16 = lane & 15;
    const int wm   = (wave & 1) * 64, wn = (wave >> 1) * 64;
    const int sr   = tid & 127;
    const int skc  = (tid >> 7) * 16;

    floatx4 acc[4][4];
    #pragma unroll
    for (int i = 0; i < 4; ++i)
        #pragma unroll
        for (int j = 0; j < 4; ++j) acc[i][j] = (floatx4){0.f, 0.f, 0.f, 0.f};

    const int gr = r0 + sr;
    const int gn = c0 + sr;

    for (int k0 = 0; k0 < K; k0 += 32) {
        const int k = k0 + skc;
        ushort8 h0, h1;
        if (gr >= M) {
            h0 = (ushort8){0,0,0,0,0,0,0,0}; h1 = h0;
        } else {
            const int ar = ridx0 ? ridx0[gr] : gr;
            if (k < C0) {
                pack16(src0 + (long)ar * s0 + o0 + k, h0, h1);
            } else if (src1b) {
                const ushort8* p = (const ushort8*)(src1b + (long)gr * s1 + o1 + (k - C0));
                h0 = p[0]; h1 = p[1];
            } else {
                pack16(src1f + (long)gr * s1 + o1 + (k - C0), h0, h1);
            }
        }
        *(ushort8*)(&As[sr * AS_STRIDE + skc])     = h0;
        *(ushort8*)(&As[sr * AS_STRIDE + skc + 8]) = h1;

        const ushort8* wp = (const ushort8*)(Wt + (long)gn * K + k0 + skc);
        *(ushort8*)(&Bs[sr * AS_STRIDE + skc])     = wp[0];
        *(ushort8*)(&Bs[sr * AS_STRIDE + skc + 8]) = wp[1];

        __syncthreads();

        short8 af[4], bfr[4];
        #pragma unroll
        for (int mt = 0; mt < 4; ++mt)
            af[mt] = *(const short8*)(&As[(wm + mt * 16 + l16) * AS_STRIDE + quad * 8]);
        #pragma unroll
        for (int nt = 0; nt < 4; ++nt)
            bfr[nt] = *(const short8*)(&Bs[(wn + nt * 16 + l16) * AS_STRIDE + quad * 8]);
        #pragma unroll
        for (int mt = 0; mt < 4; ++mt)
            #pragma unroll
            for (int nt = 0; nt < 4; ++nt)
                acc[mt][nt] = __builtin_amdgcn_mfma_f32_16x16x32_bf16(
                    af[mt], bfr[nt], acc[mt][nt], 0, 0, 0);
        __syncthreads();
    }

    #pragma unroll
    for (int nt = 0; nt < 4; ++nt) {
        const int gc = c0 + wn + nt * 16 + l16;
        const float bv = bias ? bias[gc] : 0.f;
        #pragma unroll
        for (int mt = 0; mt < 4; ++mt) {
            #pragma unroll
            for (int reg = 0; reg < 4; ++reg) {
                const int grr = r0 + wm + mt * 16 + quad * 4 + reg;
                if (grr < M) {
                    float v = acc[mt][nt][reg] + bv;
                    if (do_relu) v = fmaxf(v, 0.f);
                    if (outf) outf[(long)grr * sof + oof + gc] = v;
                    if (outb) {
                        long idx = rmode
                            ? ((long)(grr >> 3) * 4096 + (grr & 7) * 256 + gc)
                            : ((long)grr * sob + oob + gc);
                        outb[idx] = f2bf(v);
                    }
                }
            }
        }
    }
}

// ---------------------------------------------------------------------------
// Aggregation: one wave per dst node. f_out[d] = sum_e relu(P[d]+Q[src]+R[e]+b)
// * ew[e]  (+ residual). Edges CSR-sorted by dst -> no atomics.
// ---------------------------------------------------------------------------
__global__ __launch_bounds__(256) void agg_kernel(
    const unsigned short* __restrict__ pq,   // [N,512] bf16: [P | Q]
    const int* __restrict__ rowptr,
    const int* __restrict__ ssrc,
    const float* __restrict__ sew,
    const float* __restrict__ outbase,       // R raw storage + residual source
    const float* __restrict__ bias,
    float* __restrict__ out, int fofs, int rofs)
{
    const int wid  = (blockIdx.x * blockDim.x + threadIdx.x) >> 6;
    const int lane = threadIdx.x & 63;
    if (wid >= N_NODES) return;
    const int c = lane * 4;

    const ushort4v p4 = *(const ushort4v*)(pq + (long)wid * 512 + c);
    const float4 bb = *(const float4*)(bias + c);
    float pb[4] = {bf2f(p4[0]) + bb.x, bf2f(p4[1]) + bb.y,
                   bf2f(p4[2]) + bb.z, bf2f(p4[3]) + bb.w};
    float acc[4] = {0.f, 0.f, 0.f, 0.f};

    const int sEnd = rowptr[wid + 1];
    for (int s = rowptr[wid]; s < sEnd; ++s) {
        const int   srcn = ssrc[s];
        const float w    = sew[s];
        const ushort4v q4 = *(const ushort4v*)(pq + (long)srcn * 512 + 256 + c);
        const unsigned short* rp =
            (const unsigned short*)(outbase + (long)(s >> 3) * OUT_STRIDE) + (s & 7) * 256 + c;
        const ushort4v r4 = *(const ushort4v*)rp;
        #pragma unroll
        for (int j = 0; j < 4; ++j)
            acc[j] += fmaxf(pb[j] + bf2f(q4[j]) + bf2f(r4[j]), 0.f) * w;
    }
    if (rofs >= 0) {
        const float4 f4 = *(const float4*)(outbase + (long)wid * OUT_STRIDE + rofs + c);
        acc[0] += f4.x; acc[1] += f4.y; acc[2] += f4.z; acc[3] += f4.w;
    }
    float4 o; o.x = acc[0]; o.y = acc[1]; o.z = acc[2]; o.w = acc[3];
    *(float4*)(out + (long)wid * OUT_STRIDE + fofs + c) = o;
}

// ---------------------------------------------------------------------------
// Weight prep
// ---------------------------------------------------------------------------
// Wpq[n][k]: n<256 -> W0-W1 column n; n>=256 -> W1 column n-256.  W is [2F+32,256].
__global__ void wpq_prep(const float* __restrict__ W, unsigned short* __restrict__ Wpq, int F) {
    int i = blockIdx.x * blockDim.x + threadIdx.x;
    if (i < 512 * F) {
        int nn = i / F, k = i % F;
        float v = (nn < 256) ? (W[k * 256 + nn] - W[(F + k) * 256 + nn])
                             : W[(F + k) * 256 + (nn - 256)];
        Wpq[(long)nn * F + k] = f2bf(v);
    }
}

__global__ void transpose_w(const float* __restrict__ W, unsigned short* __restrict__ Wt,
                            int K, int N) {
    int i = blockIdx.x * blockDim.x + threadIdx.x;
    if (i < K * N) {
        int k = i / N, n = i % N;
        Wt[(long)n * K + k] = f2bf(W[i]);
    }
}

// ---------------------------------------------------------------------------
// CSR build
// ---------------------------------------------------------------------------
__global__ void zero_int(int* p, int n) {
    int i = blockIdx.x * blockDim.x + threadIdx.x;
    if (i < n) p[i] = 0;
}
__global__ void hist_kernel(const int* __restrict__ keys, int n, int* __restrict__ cnt) {
    int i = blockIdx.x * blockDim.x + threadIdx.x;
    if (i < n) atomicAdd(&cnt[keys[i]], 1);
}
__global__ __launch_bounds__(1024) void scan_kernel(const int* __restrict__ cnt,
                                                    int* __restrict__ rowptr,
                                                    int* __restrict__ ofs, int n) {
    __shared__ int part[1024];
    const int tid = threadIdx.x;
    const int chunk = (n + 1023) >> 10;
    int s = 0;
    for (int j = 0; j < chunk; ++j) {
        int i = tid * chunk + j;
        if (i < n) s += cnt[i];
    }
    part[tid] = s; __syncthreads();
    for (int d = 1; d < 1024; d <<= 1) {
        int v = (tid >= d) ? part[tid - d] : 0;
        __syncthreads();
        part[tid] += v;
        __syncthreads();
    }
    int run = (tid > 0) ? part[tid - 1] : 0;
    for (int j = 0; j < chunk; ++j) {
        int i = tid * chunk + j;
        if (i < n) { rowptr[i] = run; ofs[i] = run; run += cnt[i]; }
    }
    if (tid == 1023) rowptr[n] = part[1023];
}
__global__ void scatter_edges(const int* __restrict__ src, const int* __restrict__ dst,
                              const float* __restrict__ ew, int* __restrict__ ofs,
                              int* __restrict__ ssrc, float* __restrict__ sew,
                              int* __restrict__ seid) {
    int e = blockIdx.x * blockDim.x + threadIdx.x;
    if (e < N_EDGES) {
        int pos = atomicAdd(&ofs[dst[e]], 1);
        ssrc[pos] = src[e];
        sew[pos]  = ew[e];
        seid[pos] = e;
    }
}
__global__ void scatter_box(const int* __restrict__ bbox, int* __restrict__ ofs,
                            int* __restrict__ snode) {
    int i = blockIdx.x * blockDim.x + threadIdx.x;
    if (i < N_NODES) {
        int pos = atomicAdd(&ofs[bbox[i]], 1);
        snode[pos] = i;
    }
}

// ---------------------------------------------------------------------------
// Box mean via CSR (no atomics)
// ---------------------------------------------------------------------------
__global__ __launch_bounds__(256) void box_mean_csr(
    const unsigned short* __restrict__ fsbf, const int* __restrict__ bptr,
    const int* __restrict__ snode, float* __restrict__ out_super,
    float* __restrict__ fsmean)
{
    const int b = blockIdx.x >> 2;
    const int c = ((blockIdx.x & 3) << 8) + threadIdx.x;
    const int s0 = bptr[b], s1 = bptr[b + 1];
    float sum = 0.f;
    for (int s = s0; s < s1; ++s)
        sum += bf2f(fsbf[(long)snode[s] * FD + c]);
    const float mean = sum / fmaxf((float)(s1 - s0), 1.f);
    out_super[(long)b * OUT_STRIDE + HID + c] = mean;
    fsmean[(long)b * FD + c] = mean;
}

// ---------------------------------------------------------------------------
extern "C" void kernel_launch(void* const* d_in, const int* in_sizes, int n_in,
                              void* d_out, int out_size, void* d_ws, size_t ws_size,
                              hipStream_t stream) {
    const float* x      = (const float*)d_in[0];
    const int*   edges  = (const int*)d_in[1];
    const float* ew     = (const float*)d_in[2];
    const float* ea     = (const float*)d_in[3];
    const int*   bbox   = (const int*)d_in[4];
    const float* W_msg0 = (const float*)d_in[6];
    const float* b_msg0 = (const float*)d_in[7];
    const float* W_sup0 = (const float*)d_in[8];
    const float* b_sup0 = (const float*)d_in[9];
    const float* W_msg  = (const float*)d_in[10];
    const float* b_msg  = (const float*)d_in[11];
    const float* W_sup  = (const float*)d_in[12];
    const float* b_sup  = (const float*)d_in[13];
    const float* W_fuse = (const float*)d_in[14];
    const float* b_fuse = (const float*)d_in[15];
    const float* W_fsup = (const float*)d_in[16];
    const float* b_fsup = (const float*)d_in[17];

    float* out       = (float*)d_out;
    float* out_super = out + (long)N_NODES * OUT_STRIDE;

    // ---- workspace layout ----
    char* w = (char*)d_ws;
    auto alloc = [&](size_t bytes) { char* p = w; w += (bytes + 63) & ~63ULL; return p; };
    unsigned short* fsbf    = (unsigned short*)alloc((size_t)N_NODES * FD * 2);
    unsigned short* pq      = (unsigned short*)alloc((size_t)N_NODES * 512 * 2);
    unsigned short* wpq0    = (unsigned short*)alloc((size_t)512 * CIN * 2);
    unsigned short* wpq     = (unsigned short*)alloc((size_t)3 * 512 * CCH * 2);
    unsigned short* wtr     = (unsigned short*)alloc((size_t)4 * 256 * 32 * 2);
    unsigned short* wt_sup0 = (unsigned short*)alloc((size_t)256 * 320 * 2);
    unsigned short* wt_sup  = (unsigned short*)alloc((size_t)3 * 256 * 512 * 2);
    unsigned short* wt_fuse = (unsigned short*)alloc((size_t)1024 * 1024 * 2);
    unsigned short* wt_fsup = (unsigned short*)alloc((size_t)1024 * 1024 * 2);
    float* fsmean     = (float*)alloc((size_t)NBOX * FD * 4);
    float* sew        = (float*)alloc((size_t)N_EDGES * 4);
    int* cnt          = (int*)alloc((size_t)(N_NODES + 1) * 4);
    int* rowptr       = (int*)alloc((size_t)(N_NODES + 1) * 4);
    int* ofs          = (int*)alloc((size_t)(N_NODES + 1) * 4);
    int* ssrc         = (int*)alloc((size_t)N_EDGES * 4);
    int* seid         = (int*)alloc((size_t)N_EDGES * 4);
    int* bcnt         = (int*)alloc(129 * 4);
    int* bptr         = (int*)alloc(129 * 4);
    int* bofs         = (int*)alloc(129 * 4);
    int* snode        = (int*)alloc((size_t)N_NODES * 4);

    const int* srcp = edges;
    const int* dstp = edges + N_EDGES;

    // ---- weight prep ----
    wpq_prep<<<(512 * CIN + 255) / 256, 256, 0, stream>>>(W_msg0, wpq0, CIN);
    for (int i = 0; i < 3; ++i)
        wpq_prep<<<(512 * CCH + 255) / 256, 256, 0, stream>>>(
            W_msg + (long)i * 544 * 256, wpq + (long)i * 512 * CCH, CCH);
    transpose_w<<<(32 * 256 + 255) / 256, 256, 0, stream>>>(
        W_msg0 + 2 * CIN * 256, wtr, 32, 256);
    for (int i = 0; i < 3; ++i)
        transpose_w<<<(32 * 256 + 255) / 256, 256, 0, stream>>>(
            W_msg + (long)i * 544 * 256 + 2 * CCH * 256, wtr + (long)(i + 1) * 256 * 32, 32, 256);
    transpose_w<<<(320 * 256 + 255) / 256, 256, 0, stream>>>(W_sup0, wt_sup0, 320, 256);
    for (int i = 0; i < 3; ++i)
        transpose_w<<<(512 * 256 + 255) / 256, 256, 0, stream>>>(
            W_sup + (long)i * 512 * 256, wt_sup + (long)i * 256 * 512, 512, 256);
    transpose_w<<<(1024 * 1024 + 255) / 256, 256, 0, stream>>>(W_fuse, wt_fuse, 1024, 1024);
    transpose_w<<<(1024 * 1024 + 255) / 256, 256, 0, stream>>>(W_fsup, wt_fsup, 1024, 1024);

    // ---- CSR build (edges by dst; nodes by box) ----
    zero_int<<<(N_NODES + 256) / 256, 256, 0, stream>>>(cnt, N_NODES + 1);
    zero_int<<<1, 256, 0, stream>>>(bcnt, 129);
    hist_kernel<<<(N_EDGES + 255) / 256, 256, 0, stream>>>(dstp, N_EDGES, cnt);
    hist_kernel<<<(N_NODES + 255) / 256, 256, 0, stream>>>(bbox, N_NODES, bcnt);
    scan_kernel<<<1, 1024, 0, stream>>>(cnt, rowptr, ofs, N_NODES);
    scan_kernel<<<1, 1024, 0, stream>>>(bcnt, bptr, bofs, NBOX);
    scatter_edges<<<(N_EDGES + 255) / 256, 256, 0, stream>>>(srcp, dstp, ew, ofs, ssrc, sew, seid);
    scatter_box<<<(N_NODES + 255) / 256, 256, 0, stream>>>(bbox, bofs, snode);

    const int GRB = (N_NODES + 127) / 128;   // 157
    const int GEB = (N_EDGES + 127) / 128;   // 782
    unsigned short* Rb = (unsigned short*)out;   // R scratch in out[:,0:1024)

    // ---- head block ----
    mfma_dense<<<GRB * 4, 256, 0, stream>>>(x, CIN, 0, CIN, nullptr,
        nullptr, nullptr, 0, 0, wpq0, nullptr, 0,
        nullptr, 0, 0, pq, 512, 0, 0, N_NODES, CIN, 4);
    mfma_dense<<<GEB * 2, 256, 0, stream>>>(ea, A_DIM, 0, A_DIM, seid,
        nullptr, nullptr, 0, 0, wtr, nullptr, 0,
        nullptr, 0, 0, Rb, 0, 0, 1, N_EDGES, A_DIM, 2);
    agg_kernel<<<(N_NODES + 3) / 4, 256, 0, stream>>>(pq, rowptr, ssrc, sew, out,
                                                      b_msg0, out, HID, -1);
    mfma_dense<<<GRB * 2, 256, 0, stream>>>(out, OUT_STRIDE, HID, CCH, nullptr,
        x, nullptr, CIN, 0, wt_sup0, b_sup0, 1,
        nullptr, 0, 0, fsbf, FD, 0, 0, N_NODES, CCH + CIN, 2);

    // ---- ResBlocks ----
    for (int i = 0; i < 3; ++i) {
        const int fi = HID + CCH * i, fo = HID + CCH * (i + 1);
        mfma_dense<<<GRB * 4, 256, 0, stream>>>(out, OUT_STRIDE, fi, CCH, nullptr,
            nullptr, nullptr, 0, 0, wpq + (long)i * 512 * CCH, nullptr, 0,
            nullptr, 0, 0, pq, 512, 0, 0, N_NODES, CCH, 4);
        mfma_dense<<<GEB * 2, 256, 0, stream>>>(ea, A_DIM, 0, A_DIM, seid,
            nullptr, nullptr, 0, 0, wtr + (long)(i + 1) * 256 * 32, nullptr, 0,
            nullptr, 0, 0, Rb, 0, 0, 1, N_EDGES, A_DIM, 2);
        agg_kernel<<<(N_NODES + 3) / 4, 256, 0, stream>>>(pq, rowptr, ssrc, sew, out,
                                                          b_msg + i * CCH, out, fo, fi);
        mfma_dense<<<GRB * 2, 256, 0, stream>>>(out, OUT_STRIDE, fo, CCH, nullptr,
            nullptr, fsbf, FD, CCH * i, wt_sup + (long)i * 256 * 512, b_sup + i * CCH, 1,
            nullptr, 0, 0, fsbf, FD, CCH * (i + 1), 0, N_NODES, 2 * CCH, 2);
    }

    // ---- fusion ----
    mfma_dense<<<GRB * 8, 256, 0, stream>>>(out, OUT_STRIDE, HID, FD, nullptr,
        nullptr, nullptr, 0, 0, wt_fuse, b_fuse, 1,
        out, OUT_STRIDE, 0, nullptr, 0, 0, 0, N_NODES, FD, 8);

    // ---- super path ----
    box_mean_csr<<<NBOX * 4, 256, 0, stream>>>(fsbf, bptr, snode, out_super, fsmean);
    mfma_dense<<<8, 256, 0, stream>>>(fsmean, FD, 0, FD, nullptr,
        nullptr, nullptr, 0, 0, wt_fsup, b_fsup, 1,
        out_super, OUT_STRIDE, 0, nullptr, 0, 0, 0, NBOX, FD, 8);
}